// Round 13
// baseline (109.125 us; speedup 1.0000x reference)
//
#include <hip/hip_runtime.h>

typedef __attribute__((ext_vector_type(4))) _Float16 half4;
typedef __attribute__((ext_vector_type(8))) _Float16 half8;
typedef __attribute__((ext_vector_type(4))) float floatx4;
typedef __attribute__((ext_vector_type(4))) unsigned uint4v;

#define NH 8
#define CHUNKS 8

struct Split2 { unsigned hi, lo; };

// Split r0,r1 (each in [0,1]) into exact f16 hi (RTZ) + residual lo*2^11.
__device__ __forceinline__ Split2 split2(float t0, float t1) {
    unsigned hp = __builtin_bit_cast(unsigned, __builtin_amdgcn_cvt_pkrtz(t0, t1));
    float h0 = (float)__builtin_bit_cast(_Float16, (unsigned short)(hp & 0xffffu));
    float h1 = (float)__builtin_bit_cast(_Float16, (unsigned short)(hp >> 16));
    float l0 = (t0 - h0) * 2048.0f;
    float l1 = (t1 - h1) * 2048.0f;
    Split2 r;
    r.hi = hp;
    r.lo = __builtin_bit_cast(unsigned, __builtin_amdgcn_cvt_pkrtz(l0, l1));
    return r;
}

// r_i = 1/(2^min(s_i,25) + 1), one v_rcp for 4 activations (no Newton:
// validated identical absmax in r12).
// s<=25 => p<=2^25+1, P<=~2^100: no overflow. p>=1: no underflow.
__device__ __forceinline__ floatx4 quad_r(float s0, float s1, float s2, float s3) {
    s0 = fminf(s0, 25.0f); s1 = fminf(s1, 25.0f);
    s2 = fminf(s2, 25.0f); s3 = fminf(s3, 25.0f);
    float p0 = __builtin_amdgcn_exp2f(s0) + 1.0f;
    float p1 = __builtin_amdgcn_exp2f(s1) + 1.0f;
    float p2 = __builtin_amdgcn_exp2f(s2) + 1.0f;
    float p3 = __builtin_amdgcn_exp2f(s3) + 1.0f;
    float A = p0 * p1, B = p2 * p3;
    float P = A * B;
    float rp = __builtin_amdgcn_rcpf(P);
    float rA = rp * B, rB = rp * A;
    floatx4 r;
    r[0] = rA * p1; r[1] = rA * p0; r[2] = rB * p3; r[3] = rB * p2;
    return r;
}

__device__ __forceinline__ void split_w(float w, float& hi, float& lo) {
    _Float16 h = (_Float16)w;              // RNE
    hi = (float)h;
    lo = (w - hi) * 2048.0f;
}

// Build the in-place B fragment: [Hhi(4 elems) | Hlo(4 elems)]
__device__ __forceinline__ half8 mk_frag(floatx4 rq) {
    Split2 p01 = split2(rq[0], rq[1]);
    Split2 p23 = split2(rq[2], rq[3]);
    uint4v hb;
    hb.x = p01.hi; hb.y = p23.hi;   // dwords 0,1 = Hhi  (k-slots 0..15)
    hb.z = p01.lo; hb.w = p23.lo;   // dwords 2,3 = Hlo  (k-slots 16..31)
    return __builtin_bit_cast(half8, hb);
}

__global__ __launch_bounds__(256, 4) void cppn_kernel(
    const float* __restrict__ x,
    const float* __restrict__ W0,
    const float* __restrict__ b0,
    const float* __restrict__ Wh,
    const float* __restrict__ bh,
    const float* __restrict__ Wo,
    const float* __restrict__ bo,
    float* __restrict__ out)
{
    const int tid  = threadIdx.x;
    const int lane = tid & 63;
    const int col  = lane & 15;   // MFMA j (point) / A-fragment row i
    const int kg   = lane >> 4;   // k-group 0..3
    const int wib  = tid >> 6;

    const float TSCL = 2.8853900817779268f;    // 2*log2(e)
    const float NSCL = -2.0f * TSCL;           // feed-r hidden weight scale
    const float OSCL = -1.4426950408889634f;   // -log2(e)
    const float UNSC = 4.8828125e-4f;          // 2^-11

    // ---- preload hidden weights W' = NSCL*W as half8 [Wlo(4) | Whi(4)]
    //      + b' = TSCL*(b + rowsum W)  (feed-r bias fold)
    // A[i=fo][k=fi]: lane holds i=col, k=kg*4+r (+16 for upper half)
    // C/D[i][j=pt]:  lane holds i=kg*4+r, j=col
    half8   wA8[NH];
    floatx4 bC[NH];
    #pragma unroll
    for (int l = 0; l < NH; ++l) {
        const float* wrow = Wh + l*256 + col*16 + kg*4;
        float w0 = wrow[0], w1 = wrow[1], w2 = wrow[2], w3 = wrow[3];
        // row-sum of row `col` across all 16 k (for the consumer-side bias fold)
        float rs = (w0 + w1) + (w2 + w3);
        rs += __shfl_xor(rs, 16);
        rs += __shfl_xor(rs, 32);
        float h0,h1,h2,h3, lo0,lo1,lo2,lo3;
        split_w(w0*NSCL, h0, lo0);
        split_w(w1*NSCL, h1, lo1);
        split_w(w2*NSCL, h2, lo2);
        split_w(w3*NSCL, h3, lo3);
        uint4v wa;
        wa.x = __builtin_bit_cast(unsigned, __builtin_amdgcn_cvt_pkrtz(lo0, lo1)); // Wlo
        wa.y = __builtin_bit_cast(unsigned, __builtin_amdgcn_cvt_pkrtz(lo2, lo3));
        wa.z = __builtin_bit_cast(unsigned, __builtin_amdgcn_cvt_pkrtz(h0, h1));   // Whi
        wa.w = __builtin_bit_cast(unsigned, __builtin_amdgcn_cvt_pkrtz(h2, h3));
        wA8[l] = __builtin_bit_cast(half8, wa);
        floatx4 c;
        #pragma unroll
        for (int r = 0; r < 4; ++r) {
            float rs_r = __shfl(rs, kg*4 + r);           // rowsum of row kg*4+r
            c[r] = TSCL * (bh[l*16 + kg*4 + r] + rs_r);
        }
        bC[l] = c;
    }

    // input layer (consumes x directly: plain TSCL scale, no feed-r transform)
    float w0r[4][3]; float b0r[4];
    #pragma unroll
    for (int r = 0; r < 4; ++r) {
        const float* wp = W0 + (kg*4 + r)*3;
        w0r[r][0] = wp[0]*TSCL; w0r[r][1] = wp[1]*TSCL; w0r[r][2] = wp[2]*TSCL;
        b0r[r] = b0[kg*4 + r]*TSCL;
    }

    // output layer: consumes r8 -> wo' = -2*OSCL*wo, bo' = OSCL*(bo + sum wo)
    float woP[4];
    float wsum;
    {
        const float* wp = Wo + kg*4;
        float a = wp[0], b = wp[1], c2 = wp[2], d = wp[3];
        wsum = (a + b) + (c2 + d);
        wsum += __shfl_xor(wsum, 16);
        wsum += __shfl_xor(wsum, 32);
        woP[0] = a*(-2.0f*OSCL); woP[1] = b*(-2.0f*OSCL);
        woP[2] = c2*(-2.0f*OSCL); woP[3] = d*(-2.0f*OSCL);
    }
    const float boP = OSCL * (bo[0] + wsum);

    const floatx4 zeroC = {0.0f, 0.0f, 0.0f, 0.0f};
    const int base0 = (blockIdx.x * 4 + wib) * (64 * CHUNKS);

    #pragma unroll 1
    for (int c = 0; c < CHUNKS; ++c) {
        const int base = base0 + c * 64;

        // ---- input layer -> in-place split fragments (4 tiles of 16 pts) ----
        half8 hB[4];
        #pragma unroll
        for (int t = 0; t < 4; ++t) {
            const int p = base + t*16 + col;
            const float x0 = x[p*3+0], x1 = x[p*3+1], x2 = x[p*3+2];
            float a0 = fmaf(w0r[0][0],x0, fmaf(w0r[0][1],x1, fmaf(w0r[0][2],x2, b0r[0])));
            float a1 = fmaf(w0r[1][0],x0, fmaf(w0r[1][1],x1, fmaf(w0r[1][2],x2, b0r[1])));
            float a2 = fmaf(w0r[2][0],x0, fmaf(w0r[2][1],x1, fmaf(w0r[2][2],x2, b0r[2])));
            float a3 = fmaf(w0r[3][0],x0, fmaf(w0r[3][1],x1, fmaf(w0r[3][2],x2, b0r[3])));
            hB[t] = mk_frag(quad_r(a0, a1, a2, a3));
        }

        // ---- hidden layers 0..6:
        //  d = Whi*Hhi + b  (K=16, operands = aligned subvector extracts)
        //  e = Wlo*Hhi + Whi*Hlo (ONE K=32 on the full half8 fragments)
        #pragma unroll
        for (int l = 0; l < NH-1; ++l) {
            const half8 wa8 = wA8[l];
            const half4 whi = __builtin_shufflevector(wa8, wa8, 4, 5, 6, 7);
            const floatx4 bc = bC[l];
            #pragma unroll
            for (int tp = 0; tp < 2; ++tp) {
                const int u0 = tp*2, u1 = tp*2+1;
                const half4 bhi0 = __builtin_shufflevector(hB[u0], hB[u0], 0, 1, 2, 3);
                const half4 bhi1 = __builtin_shufflevector(hB[u1], hB[u1], 0, 1, 2, 3);
                floatx4 d0 = __builtin_amdgcn_mfma_f32_16x16x16f16(whi, bhi0, bc, 0,0,0);
                floatx4 d1 = __builtin_amdgcn_mfma_f32_16x16x16f16(whi, bhi1, bc, 0,0,0);
                floatx4 e0 = __builtin_amdgcn_mfma_f32_16x16x32_f16(wa8, hB[u0], zeroC, 0,0,0);
                floatx4 e1 = __builtin_amdgcn_mfma_f32_16x16x32_f16(wa8, hB[u1], zeroC, 0,0,0);

                floatx4 q0 = quad_r(fmaf(e0[0], UNSC, d0[0]),
                                    fmaf(e0[1], UNSC, d0[1]),
                                    fmaf(e0[2], UNSC, d0[2]),
                                    fmaf(e0[3], UNSC, d0[3]));
                floatx4 q1 = quad_r(fmaf(e1[0], UNSC, d1[0]),
                                    fmaf(e1[1], UNSC, d1[1]),
                                    fmaf(e1[2], UNSC, d1[2]),
                                    fmaf(e1[3], UNSC, d1[3]));
                hB[u0] = mk_frag(q0);
                hB[u1] = mk_frag(q1);
            }
        }

        // ---- last hidden layer -> r8 -> output dot (feed-r) + sigmoid ----
        float tot[4];
        {
            const half8 wa8 = wA8[NH-1];
            const half4 whi = __builtin_shufflevector(wa8, wa8, 4, 5, 6, 7);
            const floatx4 bc = bC[NH-1];
            #pragma unroll
            for (int t = 0; t < 4; ++t) {
                const half4 bhi = __builtin_shufflevector(hB[t], hB[t], 0, 1, 2, 3);
                floatx4 d = __builtin_amdgcn_mfma_f32_16x16x16f16(whi, bhi, bc, 0,0,0);
                floatx4 e = __builtin_amdgcn_mfma_f32_16x16x32_f16(wa8, hB[t], zeroC, 0,0,0);
                floatx4 r8 = quad_r(fmaf(e[0], UNSC, d[0]),
                                    fmaf(e[1], UNSC, d[1]),
                                    fmaf(e[2], UNSC, d[2]),
                                    fmaf(e[3], UNSC, d[3]));
                float acc = fmaf(woP[0], r8[0],
                            fmaf(woP[1], r8[1],
                            fmaf(woP[2], r8[2], woP[3] * r8[3])));
                acc += __shfl_xor(acc, 16);
                acc += __shfl_xor(acc, 32);
                tot[t] = acc;
            }
        }

        float s = (kg == 0) ? tot[0] : (kg == 1) ? tot[1] : (kg == 2) ? tot[2] : tot[3];
        s += boP;
        float E = __builtin_amdgcn_exp2f(s);
        out[base + lane] = __builtin_amdgcn_rcpf(1.0f + E);
    }
}

extern "C" void kernel_launch(void* const* d_in, const int* in_sizes, int n_in,
                              void* d_out, int out_size, void* d_ws, size_t ws_size,
                              hipStream_t stream) {
    const float* x  = (const float*)d_in[0];
    const float* W0 = (const float*)d_in[1];
    const float* b0 = (const float*)d_in[2];
    const float* Wh = (const float*)d_in[3];
    const float* bh = (const float*)d_in[4];
    const float* Wo = (const float*)d_in[5];
    const float* bo = (const float*)d_in[6];
    float* out = (float*)d_out;

    int n = out_size;                           // 2097152 = 1024 * 2048, exact
    int block = 256;                            // 4 waves
    long ptsPerBlock = 4L * 64 * CHUNKS;        // 2048
    int grid = (int)((n + ptsPerBlock - 1) / ptsPerBlock);   // 1024
    cppn_kernel<<<grid, block, 0, stream>>>(x, W0, b0, Wh, bh, Wo, bo, out);
}

// Round 14
// 100.204 us; speedup vs baseline: 1.0890x; 1.0890x over previous
//
#include <hip/hip_runtime.h>

typedef __attribute__((ext_vector_type(4))) _Float16 half4;
typedef __attribute__((ext_vector_type(8))) _Float16 half8;
typedef __attribute__((ext_vector_type(4))) float floatx4;
typedef __attribute__((ext_vector_type(4))) unsigned uint4v;

#define NH 8
#define CHUNKS 4

struct Split2 { unsigned hi, lo; };

// Split r0,r1 (each in [0,1]) into exact f16 hi (RTZ) + residual lo*2^11.
__device__ __forceinline__ Split2 split2(float t0, float t1) {
    unsigned hp = __builtin_bit_cast(unsigned, __builtin_amdgcn_cvt_pkrtz(t0, t1));
    float h0 = (float)__builtin_bit_cast(_Float16, (unsigned short)(hp & 0xffffu));
    float h1 = (float)__builtin_bit_cast(_Float16, (unsigned short)(hp >> 16));
    float l0 = (t0 - h0) * 2048.0f;
    float l1 = (t1 - h1) * 2048.0f;
    Split2 r;
    r.hi = hp;
    r.lo = __builtin_bit_cast(unsigned, __builtin_amdgcn_cvt_pkrtz(l0, l1));
    return r;
}

// r_i = 1/(2^min(s_i,25) + 1), one v_rcp for 4 activations (no Newton).
__device__ __forceinline__ floatx4 quad_r(float s0, float s1, float s2, float s3) {
    s0 = fminf(s0, 25.0f); s1 = fminf(s1, 25.0f);
    s2 = fminf(s2, 25.0f); s3 = fminf(s3, 25.0f);
    float p0 = __builtin_amdgcn_exp2f(s0) + 1.0f;
    float p1 = __builtin_amdgcn_exp2f(s1) + 1.0f;
    float p2 = __builtin_amdgcn_exp2f(s2) + 1.0f;
    float p3 = __builtin_amdgcn_exp2f(s3) + 1.0f;
    float A = p0 * p1, B = p2 * p3;
    float P = A * B;
    float rp = __builtin_amdgcn_rcpf(P);
    float rA = rp * B, rB = rp * A;
    floatx4 r;
    r[0] = rA * p1; r[1] = rA * p0; r[2] = rB * p3; r[3] = rB * p2;
    return r;
}

__device__ __forceinline__ void split_w(float w, float& hi, float& lo) {
    _Float16 h = (_Float16)w;              // RNE
    hi = (float)h;
    lo = (w - hi) * 2048.0f;
}

// Build the in-place B fragment: [Hhi(4 elems) | Hlo(4 elems)]
__device__ __forceinline__ half8 mk_frag(floatx4 rq) {
    Split2 p01 = split2(rq[0], rq[1]);
    Split2 p23 = split2(rq[2], rq[3]);
    uint4v hb;
    hb.x = p01.hi; hb.y = p23.hi;   // dwords 0,1 = Hhi  (k-slots 0..15)
    hb.z = p01.lo; hb.w = p23.lo;   // dwords 2,3 = Hlo  (k-slots 16..31)
    return __builtin_bit_cast(half8, hb);
}

__global__ __launch_bounds__(256)
#if __has_attribute(amdgpu_num_vgpr)
__attribute__((amdgpu_num_vgpr(60)))
#endif
void cppn_kernel(
    const float* __restrict__ x,
    const float* __restrict__ W0,
    const float* __restrict__ b0,
    const float* __restrict__ Wh,
    const float* __restrict__ bh,
    const float* __restrict__ Wo,
    const float* __restrict__ bo,
    float* __restrict__ out)
{
    // All persistent weight state in LDS -> live VGPRs ~45, below the 63 cliff.
    __shared__ uint4v  s_wA[NH][64];   // 8 KB   [Wlo(4)|Whi(4)] half8 per lane
    __shared__ floatx4 s_bC[NH][4];    // 512 B  feed-r bias per [l][kg]
    __shared__ floatx4 s_w0[4][4];     // 256 B  [r][g]: {w0*TSCL(3), b0*TSCL}
    __shared__ floatx4 s_wo4[4];       // 64 B   [g]: wo' = -2*OSCL*wo quads
    __shared__ float   s_boP;          // bo' scalar

    const int tid  = threadIdx.x;
    const int lane = tid & 63;
    const int col  = lane & 15;   // MFMA j (point) / A-fragment row i
    const int kg   = lane >> 4;   // k-group 0..3
    const int wib  = tid >> 6;

    const float TSCL = 2.8853900817779268f;    // 2*log2(e)
    const float NSCL = -2.0f * TSCL;           // feed-r hidden weight scale
    const float OSCL = -1.4426950408889634f;   // -log2(e)
    const float UNSC = 4.8828125e-4f;          // 2^-11

    // ---- stage weights into LDS ----
    if (tid < 64) {
        // wave 0: hidden weights (split, scaled) + feed-r bias fold
        #pragma unroll
        for (int l = 0; l < NH; ++l) {
            const float* wrow = Wh + l*256 + col*16 + kg*4;
            float w0v = wrow[0], w1v = wrow[1], w2v = wrow[2], w3v = wrow[3];
            float rs = (w0v + w1v) + (w2v + w3v);   // rowsum of row `col`
            rs += __shfl_xor(rs, 16);
            rs += __shfl_xor(rs, 32);
            float h0,h1,h2,h3, lo0,lo1,lo2,lo3;
            split_w(w0v*NSCL, h0, lo0);
            split_w(w1v*NSCL, h1, lo1);
            split_w(w2v*NSCL, h2, lo2);
            split_w(w3v*NSCL, h3, lo3);
            uint4v wa;
            wa.x = __builtin_bit_cast(unsigned, __builtin_amdgcn_cvt_pkrtz(lo0, lo1)); // Wlo
            wa.y = __builtin_bit_cast(unsigned, __builtin_amdgcn_cvt_pkrtz(lo2, lo3));
            wa.z = __builtin_bit_cast(unsigned, __builtin_amdgcn_cvt_pkrtz(h0, h1));   // Whi
            wa.w = __builtin_bit_cast(unsigned, __builtin_amdgcn_cvt_pkrtz(h2, h3));
            s_wA[l][tid] = wa;
            floatx4 c;
            #pragma unroll
            for (int r = 0; r < 4; ++r) {
                float rs_r = __shfl(rs, kg*4 + r);       // rowsum of row kg*4+r
                c[r] = TSCL * (bh[l*16 + kg*4 + r] + rs_r);
            }
            if (col == 0) s_bC[l][kg] = c;
        }
    } else if (tid < 80) {
        const int t = tid - 64, r = t & 3, g = t >> 2, row = g*4 + r;
        floatx4 v;
        v[0] = W0[row*3+0]*TSCL; v[1] = W0[row*3+1]*TSCL;
        v[2] = W0[row*3+2]*TSCL; v[3] = b0[row]*TSCL;
        s_w0[r][g] = v;
    } else if (tid < 84) {
        const int g = tid - 80;
        floatx4 v;
        v[0] = Wo[g*4+0]*(-2.0f*OSCL); v[1] = Wo[g*4+1]*(-2.0f*OSCL);
        v[2] = Wo[g*4+2]*(-2.0f*OSCL); v[3] = Wo[g*4+3]*(-2.0f*OSCL);
        s_wo4[g] = v;
    } else if (tid == 84) {
        float ws = 0.0f;
        #pragma unroll
        for (int i = 0; i < 16; ++i) ws += Wo[i];
        s_boP = OSCL * (bo[0] + ws);
    }
    __syncthreads();

    const floatx4 zeroC = {0.0f, 0.0f, 0.0f, 0.0f};
    const int base0 = (blockIdx.x * 4 + wib) * (64 * CHUNKS);

    #pragma unroll 1
    for (int c = 0; c < CHUNKS; ++c) {
        const int base = base0 + c * 64;

        // ---- input layer -> in-place split fragments (4 tiles of 16 pts) ----
        half8 hB[4];
        #pragma unroll
        for (int t = 0; t < 4; ++t) {
            const int p = base + t*16 + col;
            const float x0 = x[p*3+0], x1 = x[p*3+1], x2 = x[p*3+2];
            const floatx4 w0v0 = s_w0[0][kg], w0v1 = s_w0[1][kg];
            const floatx4 w0v2 = s_w0[2][kg], w0v3 = s_w0[3][kg];
            float a0 = fmaf(w0v0[0],x0, fmaf(w0v0[1],x1, fmaf(w0v0[2],x2, w0v0[3])));
            float a1 = fmaf(w0v1[0],x0, fmaf(w0v1[1],x1, fmaf(w0v1[2],x2, w0v1[3])));
            float a2 = fmaf(w0v2[0],x0, fmaf(w0v2[1],x1, fmaf(w0v2[2],x2, w0v2[3])));
            float a3 = fmaf(w0v3[0],x0, fmaf(w0v3[1],x1, fmaf(w0v3[2],x2, w0v3[3])));
            hB[t] = mk_frag(quad_r(a0, a1, a2, a3));
        }

        // ---- hidden layers 0..6:
        //  d = Whi*Hhi + b  (K=16);  e = Wlo*Hhi + Whi*Hlo (ONE K=32)
        #pragma unroll
        for (int l = 0; l < NH-1; ++l) {
            const half8 wa8 = __builtin_bit_cast(half8, s_wA[l][lane]);
            const half4 whi = __builtin_shufflevector(wa8, wa8, 4, 5, 6, 7);
            const floatx4 bc = s_bC[l][kg];
            #pragma unroll
            for (int tp = 0; tp < 2; ++tp) {
                const int u0 = tp*2, u1 = tp*2+1;
                const half4 bhi0 = __builtin_shufflevector(hB[u0], hB[u0], 0, 1, 2, 3);
                const half4 bhi1 = __builtin_shufflevector(hB[u1], hB[u1], 0, 1, 2, 3);
                floatx4 d0 = __builtin_amdgcn_mfma_f32_16x16x16f16(whi, bhi0, bc, 0,0,0);
                floatx4 d1 = __builtin_amdgcn_mfma_f32_16x16x16f16(whi, bhi1, bc, 0,0,0);
                floatx4 e0 = __builtin_amdgcn_mfma_f32_16x16x32_f16(wa8, hB[u0], zeroC, 0,0,0);
                floatx4 e1 = __builtin_amdgcn_mfma_f32_16x16x32_f16(wa8, hB[u1], zeroC, 0,0,0);

                floatx4 q0 = quad_r(fmaf(e0[0], UNSC, d0[0]),
                                    fmaf(e0[1], UNSC, d0[1]),
                                    fmaf(e0[2], UNSC, d0[2]),
                                    fmaf(e0[3], UNSC, d0[3]));
                floatx4 q1 = quad_r(fmaf(e1[0], UNSC, d1[0]),
                                    fmaf(e1[1], UNSC, d1[1]),
                                    fmaf(e1[2], UNSC, d1[2]),
                                    fmaf(e1[3], UNSC, d1[3]));
                hB[u0] = mk_frag(q0);
                hB[u1] = mk_frag(q1);
            }
        }

        // ---- last hidden layer -> r8 -> output dot (feed-r) + sigmoid ----
        float tot[4];
        {
            const half8 wa8 = __builtin_bit_cast(half8, s_wA[NH-1][lane]);
            const half4 whi = __builtin_shufflevector(wa8, wa8, 4, 5, 6, 7);
            const floatx4 bc = s_bC[NH-1][kg];
            const floatx4 wov = s_wo4[kg];
            #pragma unroll
            for (int t = 0; t < 4; ++t) {
                const half4 bhi = __builtin_shufflevector(hB[t], hB[t], 0, 1, 2, 3);
                floatx4 d = __builtin_amdgcn_mfma_f32_16x16x16f16(whi, bhi, bc, 0,0,0);
                floatx4 e = __builtin_amdgcn_mfma_f32_16x16x32_f16(wa8, hB[t], zeroC, 0,0,0);
                floatx4 r8 = quad_r(fmaf(e[0], UNSC, d[0]),
                                    fmaf(e[1], UNSC, d[1]),
                                    fmaf(e[2], UNSC, d[2]),
                                    fmaf(e[3], UNSC, d[3]));
                float acc = fmaf(wov[0], r8[0],
                            fmaf(wov[1], r8[1],
                            fmaf(wov[2], r8[2], wov[3] * r8[3])));
                acc += __shfl_xor(acc, 16);
                acc += __shfl_xor(acc, 32);
                tot[t] = acc;
            }
        }

        float s = (kg == 0) ? tot[0] : (kg == 1) ? tot[1] : (kg == 2) ? tot[2] : tot[3];
        s += s_boP;
        float E = __builtin_amdgcn_exp2f(s);
        out[base + lane] = __builtin_amdgcn_rcpf(1.0f + E);
    }
}

extern "C" void kernel_launch(void* const* d_in, const int* in_sizes, int n_in,
                              void* d_out, int out_size, void* d_ws, size_t ws_size,
                              hipStream_t stream) {
    const float* x  = (const float*)d_in[0];
    const float* W0 = (const float*)d_in[1];
    const float* b0 = (const float*)d_in[2];
    const float* Wh = (const float*)d_in[3];
    const float* bh = (const float*)d_in[4];
    const float* Wo = (const float*)d_in[5];
    const float* bo = (const float*)d_in[6];
    float* out = (float*)d_out;

    int n = out_size;                           // 2097152 = 2048 * 1024, exact
    int block = 256;                            // 4 waves
    long ptsPerBlock = 4L * 64 * CHUNKS;        // 1024
    int grid = (int)((n + ptsPerBlock - 1) / ptsPerBlock);   // 2048 = 8/CU
    cppn_kernel<<<grid, block, 0, stream>>>(x, W0, b0, Wh, bh, Wo, bo, out);
}

// Round 16
// 98.149 us; speedup vs baseline: 1.1118x; 1.0209x over previous
//
#include <hip/hip_runtime.h>

typedef __attribute__((ext_vector_type(4))) _Float16 half4;
typedef __attribute__((ext_vector_type(8))) _Float16 half8;
typedef __attribute__((ext_vector_type(4))) float floatx4;
typedef __attribute__((ext_vector_type(4))) unsigned uint4v;

#define NH 8
#define CHUNKS 4

struct Split2 { unsigned hi, lo; };

// Split r0,r1 (each in [0,1]) into exact f16 hi (RTZ) + residual lo*2^11.
// The 2^11 scale is REQUIRED: unscaled residuals fall into the f16 denormal
// window (<2^-14) and are flushed by MFMA (r15: absmax 1.0).
__device__ __forceinline__ Split2 split2(float t0, float t1) {
    unsigned hp = __builtin_bit_cast(unsigned, __builtin_amdgcn_cvt_pkrtz(t0, t1));
    float h0 = (float)__builtin_bit_cast(_Float16, (unsigned short)(hp & 0xffffu));
    float h1 = (float)__builtin_bit_cast(_Float16, (unsigned short)(hp >> 16));
    float l0 = (t0 - h0) * 2048.0f;
    float l1 = (t1 - h1) * 2048.0f;
    Split2 r;
    r.hi = hp;
    r.lo = __builtin_bit_cast(unsigned, __builtin_amdgcn_cvt_pkrtz(l0, l1));
    return r;
}

// r_i = 1/(2^min(s_i,25) + 1), one v_rcp for 4 activations (no Newton).
__device__ __forceinline__ floatx4 quad_r(float s0, float s1, float s2, float s3) {
    s0 = fminf(s0, 25.0f); s1 = fminf(s1, 25.0f);
    s2 = fminf(s2, 25.0f); s3 = fminf(s3, 25.0f);
    float p0 = __builtin_amdgcn_exp2f(s0) + 1.0f;
    float p1 = __builtin_amdgcn_exp2f(s1) + 1.0f;
    float p2 = __builtin_amdgcn_exp2f(s2) + 1.0f;
    float p3 = __builtin_amdgcn_exp2f(s3) + 1.0f;
    float A = p0 * p1, B = p2 * p3;
    float P = A * B;
    float rp = __builtin_amdgcn_rcpf(P);
    float rA = rp * B, rB = rp * A;
    floatx4 r;
    r[0] = rA * p1; r[1] = rA * p0; r[2] = rB * p3; r[3] = rB * p2;
    return r;
}

__device__ __forceinline__ void split_w(float w, float& hi, float& lo) {
    _Float16 h = (_Float16)w;              // RNE
    hi = (float)h;
    lo = (w - hi) * 2048.0f;
}

// Full-precision B fragment: [Hhi(4) | Hlo(4)], lo scaled 2^11.
__device__ __forceinline__ half8 mk_frag(floatx4 rq) {
    Split2 p01 = split2(rq[0], rq[1]);
    Split2 p23 = split2(rq[2], rq[3]);
    uint4v hb;
    hb.x = p01.hi; hb.y = p23.hi;   // dwords 0,1 = Hhi  (k-slots 0..15)
    hb.z = p01.lo; hb.w = p23.lo;   // dwords 2,3 = Hlo  (k-slots 16..31)
    return __builtin_bit_cast(half8, hb);
}

// Tail fragment: f16 hi only (consumers use the K=16 d-MFMA exclusively).
// RNE error <= 2^-12, amplified ~10.6x (layer5) / 3.25x (layer6) -> <3e-3.
__device__ __forceinline__ half8 mk_frag_hi(floatx4 rq) {
    uint4v hb;
    hb.x = __builtin_bit_cast(unsigned, __builtin_amdgcn_cvt_pkrtz(rq[0], rq[1]));
    hb.y = __builtin_bit_cast(unsigned, __builtin_amdgcn_cvt_pkrtz(rq[2], rq[3]));
    hb.z = 0u; hb.w = 0u;           // lo slots unused by tail consumers
    return __builtin_bit_cast(half8, hb);
}

__global__ __launch_bounds__(256)
#if __has_attribute(amdgpu_num_vgpr)
__attribute__((amdgpu_num_vgpr(60)))
#endif
void cppn_kernel(
    const float* __restrict__ x,
    const float* __restrict__ W0,
    const float* __restrict__ b0,
    const float* __restrict__ Wh,
    const float* __restrict__ bh,
    const float* __restrict__ Wo,
    const float* __restrict__ bo,
    float* __restrict__ out)
{
    // All persistent weight state in LDS.
    __shared__ uint4v  s_wA[NH][64];   // 8 KB   [Wlo(4)|Whi(4)] half8 per lane
    __shared__ floatx4 s_bC[NH][4];    // 512 B  feed-r bias per [l][kg]
    __shared__ floatx4 s_w0[4][4];     // 256 B  [r][g]: {w0*TSCL(3), b0*TSCL}
    __shared__ floatx4 s_wo4[4];       // 64 B   [g]: wo' = -2*OSCL*wo quads
    __shared__ float   s_boP;          // bo' scalar

    const int tid  = threadIdx.x;
    const int lane = tid & 63;
    const int col  = lane & 15;   // MFMA j (point) / A-fragment row i
    const int kg   = lane >> 4;   // k-group 0..3
    const int wib  = tid >> 6;

    const float TSCL = 2.8853900817779268f;    // 2*log2(e)
    const float NSCL = -2.0f * TSCL;           // feed-r hidden weight scale
    const float OSCL = -1.4426950408889634f;   // -log2(e)
    const float UNSC = 4.8828125e-4f;          // 2^-11

    // ---- stage weights into LDS ----
    if (tid < 64) {
        // wave 0: hidden weights (split, scaled) + feed-r bias fold
        #pragma unroll
        for (int l = 0; l < NH; ++l) {
            const float* wrow = Wh + l*256 + col*16 + kg*4;
            float w0v = wrow[0], w1v = wrow[1], w2v = wrow[2], w3v = wrow[3];
            float rs = (w0v + w1v) + (w2v + w3v);   // rowsum of row `col`
            rs += __shfl_xor(rs, 16);
            rs += __shfl_xor(rs, 32);
            float h0,h1,h2,h3, lo0,lo1,lo2,lo3;
            split_w(w0v*NSCL, h0, lo0);
            split_w(w1v*NSCL, h1, lo1);
            split_w(w2v*NSCL, h2, lo2);
            split_w(w3v*NSCL, h3, lo3);
            uint4v wa;
            wa.x = __builtin_bit_cast(unsigned, __builtin_amdgcn_cvt_pkrtz(lo0, lo1)); // Wlo
            wa.y = __builtin_bit_cast(unsigned, __builtin_amdgcn_cvt_pkrtz(lo2, lo3));
            wa.z = __builtin_bit_cast(unsigned, __builtin_amdgcn_cvt_pkrtz(h0, h1));   // Whi
            wa.w = __builtin_bit_cast(unsigned, __builtin_amdgcn_cvt_pkrtz(h2, h3));
            s_wA[l][tid] = wa;
            floatx4 c;
            #pragma unroll
            for (int r = 0; r < 4; ++r) {
                float rs_r = __shfl(rs, kg*4 + r);       // rowsum of row kg*4+r
                c[r] = TSCL * (bh[l*16 + kg*4 + r] + rs_r);
            }
            if (col == 0) s_bC[l][kg] = c;
        }
    } else if (tid < 80) {
        const int t = tid - 64, r = t & 3, g = t >> 2, row = g*4 + r;
        floatx4 v;
        v[0] = W0[row*3+0]*TSCL; v[1] = W0[row*3+1]*TSCL;
        v[2] = W0[row*3+2]*TSCL; v[3] = b0[row]*TSCL;
        s_w0[r][g] = v;
    } else if (tid < 84) {
        const int g = tid - 80;
        floatx4 v;
        v[0] = Wo[g*4+0]*(-2.0f*OSCL); v[1] = Wo[g*4+1]*(-2.0f*OSCL);
        v[2] = Wo[g*4+2]*(-2.0f*OSCL); v[3] = Wo[g*4+3]*(-2.0f*OSCL);
        s_wo4[g] = v;
    } else if (tid == 84) {
        float ws = 0.0f;
        #pragma unroll
        for (int i = 0; i < 16; ++i) ws += Wo[i];
        s_boP = OSCL * (bo[0] + ws);
    }
    __syncthreads();

    const int base0 = (blockIdx.x * 4 + wib) * (64 * CHUNKS);

    #pragma unroll 1
    for (int c = 0; c < CHUNKS; ++c) {
        const int base = base0 + c * 64;

        // ---- input layer -> split fragments (4 tiles of 16 pts) ----
        half8 hB[4];
        #pragma unroll
        for (int t = 0; t < 4; ++t) {
            const int p = base + t*16 + col;
            const float x0 = x[p*3+0], x1 = x[p*3+1], x2 = x[p*3+2];
            const floatx4 w0v0 = s_w0[0][kg], w0v1 = s_w0[1][kg];
            const floatx4 w0v2 = s_w0[2][kg], w0v3 = s_w0[3][kg];
            float a0 = fmaf(w0v0[0],x0, fmaf(w0v0[1],x1, fmaf(w0v0[2],x2, w0v0[3])));
            float a1 = fmaf(w0v1[0],x0, fmaf(w0v1[1],x1, fmaf(w0v1[2],x2, w0v1[3])));
            float a2 = fmaf(w0v2[0],x0, fmaf(w0v2[1],x1, fmaf(w0v2[2],x2, w0v2[3])));
            float a3 = fmaf(w0v3[0],x0, fmaf(w0v3[1],x1, fmaf(w0v3[2],x2, w0v3[3])));
            hB[t] = mk_frag(quad_r(a0, a1, a2, a3));
        }

        // ---- hidden layers 0..4: full split precision (d K=16 + e K=32) ----
        #pragma unroll
        for (int l = 0; l < 5; ++l) {
            const half8 wa8 = __builtin_bit_cast(half8, s_wA[l][lane]);
            const half4 whi = __builtin_shufflevector(wa8, wa8, 4, 5, 6, 7);
            const floatx4 bc = s_bC[l][kg];
            #pragma unroll
            for (int tp = 0; tp < 2; ++tp) {
                const int u0 = tp*2, u1 = tp*2+1;
                const half4 bhi0 = __builtin_shufflevector(hB[u0], hB[u0], 0, 1, 2, 3);
                const half4 bhi1 = __builtin_shufflevector(hB[u1], hB[u1], 0, 1, 2, 3);
                floatx4 d0 = __builtin_amdgcn_mfma_f32_16x16x16f16(whi, bhi0, bc, 0,0,0);
                floatx4 d1 = __builtin_amdgcn_mfma_f32_16x16x16f16(whi, bhi1, bc, 0,0,0);
                floatx4 e0 = __builtin_amdgcn_mfma_f32_16x16x32_f16(wa8, hB[u0], {0.f,0.f,0.f,0.f}, 0,0,0);
                floatx4 e1 = __builtin_amdgcn_mfma_f32_16x16x32_f16(wa8, hB[u1], {0.f,0.f,0.f,0.f}, 0,0,0);
                floatx4 q0 = quad_r(fmaf(e0[0], UNSC, d0[0]),
                                    fmaf(e0[1], UNSC, d0[1]),
                                    fmaf(e0[2], UNSC, d0[2]),
                                    fmaf(e0[3], UNSC, d0[3]));
                floatx4 q1 = quad_r(fmaf(e1[0], UNSC, d1[0]),
                                    fmaf(e1[1], UNSC, d1[1]),
                                    fmaf(e1[2], UNSC, d1[2]),
                                    fmaf(e1[3], UNSC, d1[3]));
                hB[u0] = mk_frag(q0);
                hB[u1] = mk_frag(q1);
            }
        }

        // ---- hidden layer 5: split consume, HI-ONLY produce ----
        {
            const half8 wa8 = __builtin_bit_cast(half8, s_wA[5][lane]);
            const half4 whi = __builtin_shufflevector(wa8, wa8, 4, 5, 6, 7);
            const floatx4 bc = s_bC[5][kg];
            #pragma unroll
            for (int t = 0; t < 4; ++t) {
                const half4 bhi = __builtin_shufflevector(hB[t], hB[t], 0, 1, 2, 3);
                floatx4 d = __builtin_amdgcn_mfma_f32_16x16x16f16(whi, bhi, bc, 0,0,0);
                floatx4 e = __builtin_amdgcn_mfma_f32_16x16x32_f16(wa8, hB[t], {0.f,0.f,0.f,0.f}, 0,0,0);
                floatx4 q = quad_r(fmaf(e[0], UNSC, d[0]),
                                   fmaf(e[1], UNSC, d[1]),
                                   fmaf(e[2], UNSC, d[2]),
                                   fmaf(e[3], UNSC, d[3]));
                hB[t] = mk_frag_hi(q);
            }
        }

        // ---- hidden layer 6: f16-only (d-MFMA only, no e, no merge) ----
        {
            const half8 wa8 = __builtin_bit_cast(half8, s_wA[6][lane]);
            const half4 whi = __builtin_shufflevector(wa8, wa8, 4, 5, 6, 7);
            const floatx4 bc = s_bC[6][kg];
            #pragma unroll
            for (int t = 0; t < 4; ++t) {
                const half4 bhi = __builtin_shufflevector(hB[t], hB[t], 0, 1, 2, 3);
                floatx4 d = __builtin_amdgcn_mfma_f32_16x16x16f16(whi, bhi, bc, 0,0,0);
                hB[t] = mk_frag_hi(quad_r(d[0], d[1], d[2], d[3]));
            }
        }

        // ---- hidden layer 7 (f16-only) -> r8 -> output dot + sigmoid ----
        float tot[4];
        {
            const half8 wa8 = __builtin_bit_cast(half8, s_wA[7][lane]);
            const half4 whi = __builtin_shufflevector(wa8, wa8, 4, 5, 6, 7);
            const floatx4 bc = s_bC[7][kg];
            const floatx4 wov = s_wo4[kg];
            #pragma unroll
            for (int t = 0; t < 4; ++t) {
                const half4 bhi = __builtin_shufflevector(hB[t], hB[t], 0, 1, 2, 3);
                floatx4 d = __builtin_amdgcn_mfma_f32_16x16x16f16(whi, bhi, bc, 0,0,0);
                floatx4 r8 = quad_r(d[0], d[1], d[2], d[3]);
                float acc = fmaf(wov[0], r8[0],
                            fmaf(wov[1], r8[1],
                            fmaf(wov[2], r8[2], wov[3] * r8[3])));
                acc += __shfl_xor(acc, 16);
                acc += __shfl_xor(acc, 32);
                tot[t] = acc;
            }
        }

        float s = (kg == 0) ? tot[0] : (kg == 1) ? tot[1] : (kg == 2) ? tot[2] : tot[3];
        s += s_boP;
        float E = __builtin_amdgcn_exp2f(s);
        out[base + lane] = __builtin_amdgcn_rcpf(1.0f + E);
    }
}

extern "C" void kernel_launch(void* const* d_in, const int* in_sizes, int n_in,
                              void* d_out, int out_size, void* d_ws, size_t ws_size,
                              hipStream_t stream) {
    const float* x  = (const float*)d_in[0];
    const float* W0 = (const float*)d_in[1];
    const float* b0 = (const float*)d_in[2];
    const float* Wh = (const float*)d_in[3];
    const float* bh = (const float*)d_in[4];
    const float* Wo = (const float*)d_in[5];
    const float* bo = (const float*)d_in[6];
    float* out = (float*)d_out;

    int n = out_size;                           // 2097152 = 2048 * 1024, exact
    int block = 256;                            // 4 waves
    long ptsPerBlock = 4L * 64 * CHUNKS;        // 1024
    int grid = (int)((n + ptsPerBlock - 1) / ptsPerBlock);   // 2048 = 8/CU
    cppn_kernel<<<grid, block, 0, stream>>>(x, W0, b0, Wh, bh, Wo, bo, out);
}

// Round 17
// 93.510 us; speedup vs baseline: 1.1670x; 1.0496x over previous
//
#include <hip/hip_runtime.h>

typedef __attribute__((ext_vector_type(4))) _Float16 half4;
typedef __attribute__((ext_vector_type(8))) _Float16 half8;
typedef __attribute__((ext_vector_type(4))) float floatx4;
typedef __attribute__((ext_vector_type(4))) unsigned uint4v;

#define NH 8
#define CHUNKS 4

struct Split2 { unsigned hi, lo; };

// Split r0,r1 (each in [0,1]) into exact f16 hi (RTZ) + residual lo*2^11.
// The 2^11 scale is REQUIRED: unscaled residuals fall into the f16 denormal
// window (<2^-14) and are flushed by MFMA (r15: absmax 1.0).
__device__ __forceinline__ Split2 split2(float t0, float t1) {
    unsigned hp = __builtin_bit_cast(unsigned, __builtin_amdgcn_cvt_pkrtz(t0, t1));
    float h0 = (float)__builtin_bit_cast(_Float16, (unsigned short)(hp & 0xffffu));
    float h1 = (float)__builtin_bit_cast(_Float16, (unsigned short)(hp >> 16));
    float l0 = (t0 - h0) * 2048.0f;
    float l1 = (t1 - h1) * 2048.0f;
    Split2 r;
    r.hi = hp;
    r.lo = __builtin_bit_cast(unsigned, __builtin_amdgcn_cvt_pkrtz(l0, l1));
    return r;
}

// r_i = 1/(2^min(s_i,25) + 1), one v_rcp for 4 activations (no Newton).
__device__ __forceinline__ floatx4 quad_r(float s0, float s1, float s2, float s3) {
    s0 = fminf(s0, 25.0f); s1 = fminf(s1, 25.0f);
    s2 = fminf(s2, 25.0f); s3 = fminf(s3, 25.0f);
    float p0 = __builtin_amdgcn_exp2f(s0) + 1.0f;
    float p1 = __builtin_amdgcn_exp2f(s1) + 1.0f;
    float p2 = __builtin_amdgcn_exp2f(s2) + 1.0f;
    float p3 = __builtin_amdgcn_exp2f(s3) + 1.0f;
    float A = p0 * p1, B = p2 * p3;
    float P = A * B;
    float rp = __builtin_amdgcn_rcpf(P);
    float rA = rp * B, rB = rp * A;
    floatx4 r;
    r[0] = rA * p1; r[1] = rA * p0; r[2] = rB * p3; r[3] = rB * p2;
    return r;
}

__device__ __forceinline__ void split_w(float w, float& hi, float& lo) {
    _Float16 h = (_Float16)w;              // RNE
    hi = (float)h;
    lo = (w - hi) * 2048.0f;
}

// Full-precision B fragment: [Hhi(4) | Hlo(4)], lo scaled 2^11.
__device__ __forceinline__ half8 mk_frag(floatx4 rq) {
    Split2 p01 = split2(rq[0], rq[1]);
    Split2 p23 = split2(rq[2], rq[3]);
    uint4v hb;
    hb.x = p01.hi; hb.y = p23.hi;   // dwords 0,1 = Hhi  (k-slots 0..15)
    hb.z = p01.lo; hb.w = p23.lo;   // dwords 2,3 = Hlo  (k-slots 16..31)
    return __builtin_bit_cast(half8, hb);
}

// Tail fragment: f16 hi only, lo slots zero. A consumer's K=32 e-MFMA then
// computes exactly Wlo*Hhi (weight residual retained, H residual dropped).
__device__ __forceinline__ half8 mk_frag_hi(floatx4 rq) {
    uint4v hb;
    hb.x = __builtin_bit_cast(unsigned, __builtin_amdgcn_cvt_pkrtz(rq[0], rq[1]));
    hb.y = __builtin_bit_cast(unsigned, __builtin_amdgcn_cvt_pkrtz(rq[2], rq[3]));
    hb.z = 0u; hb.w = 0u;
    return __builtin_bit_cast(half8, hb);
}

__global__ __launch_bounds__(256)
#if __has_attribute(amdgpu_num_vgpr)
__attribute__((amdgpu_num_vgpr(60)))
#endif
void cppn_kernel(
    const float* __restrict__ x,
    const float* __restrict__ W0,
    const float* __restrict__ b0,
    const float* __restrict__ Wh,
    const float* __restrict__ bh,
    const float* __restrict__ Wo,
    const float* __restrict__ bo,
    float* __restrict__ out)
{
    // All persistent weight state in LDS.
    __shared__ uint4v  s_wA[NH][64];   // 8 KB   [Wlo(4)|Whi(4)] half8 per lane
    __shared__ floatx4 s_bC[NH][4];    // 512 B  feed-r bias per [l][kg]
    __shared__ floatx4 s_w0[4][4];     // 256 B  [r][g]: {w0*TSCL(3), b0*TSCL}
    __shared__ floatx4 s_wo4[4];       // 64 B   [g]: wo' = -2*OSCL*wo quads
    __shared__ float   s_boP;          // bo' scalar

    const int tid  = threadIdx.x;
    const int lane = tid & 63;
    const int col  = lane & 15;   // MFMA j (point) / A-fragment row i
    const int kg   = lane >> 4;   // k-group 0..3
    const int wib  = tid >> 6;

    const float TSCL = 2.8853900817779268f;    // 2*log2(e)
    const float NSCL = -2.0f * TSCL;           // feed-r hidden weight scale
    const float OSCL = -1.4426950408889634f;   // -log2(e)
    const float UNSC = 4.8828125e-4f;          // 2^-11

    // ---- stage weights into LDS ----
    if (tid < 64) {
        // wave 0: hidden weights (split, scaled) + feed-r bias fold
        #pragma unroll
        for (int l = 0; l < NH; ++l) {
            const float* wrow = Wh + l*256 + col*16 + kg*4;
            float w0v = wrow[0], w1v = wrow[1], w2v = wrow[2], w3v = wrow[3];
            float rs = (w0v + w1v) + (w2v + w3v);   // rowsum of row `col`
            rs += __shfl_xor(rs, 16);
            rs += __shfl_xor(rs, 32);
            float h0,h1,h2,h3, lo0,lo1,lo2,lo3;
            split_w(w0v*NSCL, h0, lo0);
            split_w(w1v*NSCL, h1, lo1);
            split_w(w2v*NSCL, h2, lo2);
            split_w(w3v*NSCL, h3, lo3);
            uint4v wa;
            wa.x = __builtin_bit_cast(unsigned, __builtin_amdgcn_cvt_pkrtz(lo0, lo1)); // Wlo
            wa.y = __builtin_bit_cast(unsigned, __builtin_amdgcn_cvt_pkrtz(lo2, lo3));
            wa.z = __builtin_bit_cast(unsigned, __builtin_amdgcn_cvt_pkrtz(h0, h1));   // Whi
            wa.w = __builtin_bit_cast(unsigned, __builtin_amdgcn_cvt_pkrtz(h2, h3));
            s_wA[l][tid] = wa;
            floatx4 c;
            #pragma unroll
            for (int r = 0; r < 4; ++r) {
                float rs_r = __shfl(rs, kg*4 + r);       // rowsum of row kg*4+r
                c[r] = TSCL * (bh[l*16 + kg*4 + r] + rs_r);
            }
            if (col == 0) s_bC[l][kg] = c;
        }
    } else if (tid < 80) {
        const int t = tid - 64, r = t & 3, g = t >> 2, row = g*4 + r;
        floatx4 v;
        v[0] = W0[row*3+0]*TSCL; v[1] = W0[row*3+1]*TSCL;
        v[2] = W0[row*3+2]*TSCL; v[3] = b0[row]*TSCL;
        s_w0[r][g] = v;
    } else if (tid < 84) {
        const int g = tid - 80;
        floatx4 v;
        v[0] = Wo[g*4+0]*(-2.0f*OSCL); v[1] = Wo[g*4+1]*(-2.0f*OSCL);
        v[2] = Wo[g*4+2]*(-2.0f*OSCL); v[3] = Wo[g*4+3]*(-2.0f*OSCL);
        s_wo4[g] = v;
    } else if (tid == 84) {
        float ws = 0.0f;
        #pragma unroll
        for (int i = 0; i < 16; ++i) ws += Wo[i];
        s_boP = OSCL * (bo[0] + ws);
    }
    __syncthreads();

    const int base0 = (blockIdx.x * 4 + wib) * (64 * CHUNKS);

    #pragma unroll 1
    for (int c = 0; c < CHUNKS; ++c) {
        const int base = base0 + c * 64;

        // ---- input layer -> split fragments (4 tiles of 16 pts) ----
        half8 hB[4];
        #pragma unroll
        for (int t = 0; t < 4; ++t) {
            const int p = base + t*16 + col;
            const float x0 = x[p*3+0], x1 = x[p*3+1], x2 = x[p*3+2];
            const floatx4 w0v0 = s_w0[0][kg], w0v1 = s_w0[1][kg];
            const floatx4 w0v2 = s_w0[2][kg], w0v3 = s_w0[3][kg];
            float a0 = fmaf(w0v0[0],x0, fmaf(w0v0[1],x1, fmaf(w0v0[2],x2, w0v0[3])));
            float a1 = fmaf(w0v1[0],x0, fmaf(w0v1[1],x1, fmaf(w0v1[2],x2, w0v1[3])));
            float a2 = fmaf(w0v2[0],x0, fmaf(w0v2[1],x1, fmaf(w0v2[2],x2, w0v2[3])));
            float a3 = fmaf(w0v3[0],x0, fmaf(w0v3[1],x1, fmaf(w0v3[2],x2, w0v3[3])));
            hB[t] = mk_frag(quad_r(a0, a1, a2, a3));
        }

        // ---- hidden layers 0..3: full split precision (d K=16 + e K=32) ----
        #pragma unroll
        for (int l = 0; l < 4; ++l) {
            const half8 wa8 = __builtin_bit_cast(half8, s_wA[l][lane]);
            const half4 whi = __builtin_shufflevector(wa8, wa8, 4, 5, 6, 7);
            const floatx4 bc = s_bC[l][kg];
            #pragma unroll
            for (int tp = 0; tp < 2; ++tp) {
                const int u0 = tp*2, u1 = tp*2+1;
                const half4 bhi0 = __builtin_shufflevector(hB[u0], hB[u0], 0, 1, 2, 3);
                const half4 bhi1 = __builtin_shufflevector(hB[u1], hB[u1], 0, 1, 2, 3);
                floatx4 d0 = __builtin_amdgcn_mfma_f32_16x16x16f16(whi, bhi0, bc, 0,0,0);
                floatx4 d1 = __builtin_amdgcn_mfma_f32_16x16x16f16(whi, bhi1, bc, 0,0,0);
                floatx4 e0 = __builtin_amdgcn_mfma_f32_16x16x32_f16(wa8, hB[u0], {0.f,0.f,0.f,0.f}, 0,0,0);
                floatx4 e1 = __builtin_amdgcn_mfma_f32_16x16x32_f16(wa8, hB[u1], {0.f,0.f,0.f,0.f}, 0,0,0);
                floatx4 q0 = quad_r(fmaf(e0[0], UNSC, d0[0]),
                                    fmaf(e0[1], UNSC, d0[1]),
                                    fmaf(e0[2], UNSC, d0[2]),
                                    fmaf(e0[3], UNSC, d0[3]));
                floatx4 q1 = quad_r(fmaf(e1[0], UNSC, d1[0]),
                                    fmaf(e1[1], UNSC, d1[1]),
                                    fmaf(e1[2], UNSC, d1[2]),
                                    fmaf(e1[3], UNSC, d1[3]));
                hB[u0] = mk_frag(q0);
                hB[u1] = mk_frag(q1);
            }
        }

        // ---- hidden layers 4..5: split consume (e keeps Wlo*Hhi), HI-ONLY produce ----
        #pragma unroll
        for (int l = 4; l < 6; ++l) {
            const half8 wa8 = __builtin_bit_cast(half8, s_wA[l][lane]);
            const half4 whi = __builtin_shufflevector(wa8, wa8, 4, 5, 6, 7);
            const floatx4 bc = s_bC[l][kg];
            #pragma unroll
            for (int t = 0; t < 4; ++t) {
                const half4 bhi = __builtin_shufflevector(hB[t], hB[t], 0, 1, 2, 3);
                floatx4 d = __builtin_amdgcn_mfma_f32_16x16x16f16(whi, bhi, bc, 0,0,0);
                floatx4 e = __builtin_amdgcn_mfma_f32_16x16x32_f16(wa8, hB[t], {0.f,0.f,0.f,0.f}, 0,0,0);
                floatx4 q = quad_r(fmaf(e[0], UNSC, d[0]),
                                   fmaf(e[1], UNSC, d[1]),
                                   fmaf(e[2], UNSC, d[2]),
                                   fmaf(e[3], UNSC, d[3]));
                hB[t] = mk_frag_hi(q);
            }
        }

        // ---- hidden layer 6: f16-only (d-MFMA only, no e, no merge) ----
        {
            const half8 wa8 = __builtin_bit_cast(half8, s_wA[6][lane]);
            const half4 whi = __builtin_shufflevector(wa8, wa8, 4, 5, 6, 7);
            const floatx4 bc = s_bC[6][kg];
            #pragma unroll
            for (int t = 0; t < 4; ++t) {
                const half4 bhi = __builtin_shufflevector(hB[t], hB[t], 0, 1, 2, 3);
                floatx4 d = __builtin_amdgcn_mfma_f32_16x16x16f16(whi, bhi, bc, 0,0,0);
                hB[t] = mk_frag_hi(quad_r(d[0], d[1], d[2], d[3]));
            }
        }

        // ---- hidden layer 7 (f16-only) -> r8 -> output dot + sigmoid ----
        float tot[4];
        {
            const half8 wa8 = __builtin_bit_cast(half8, s_wA[7][lane]);
            const half4 whi = __builtin_shufflevector(wa8, wa8, 4, 5, 6, 7);
            const floatx4 bc = s_bC[7][kg];
            const floatx4 wov = s_wo4[kg];
            #pragma unroll
            for (int t = 0; t < 4; ++t) {
                const half4 bhi = __builtin_shufflevector(hB[t], hB[t], 0, 1, 2, 3);
                floatx4 d = __builtin_amdgcn_mfma_f32_16x16x16f16(whi, bhi, bc, 0,0,0);
                floatx4 r8 = quad_r(d[0], d[1], d[2], d[3]);
                float acc = fmaf(wov[0], r8[0],
                            fmaf(wov[1], r8[1],
                            fmaf(wov[2], r8[2], wov[3] * r8[3])));
                acc += __shfl_xor(acc, 16);
                acc += __shfl_xor(acc, 32);
                tot[t] = acc;
            }
        }

        float s = (kg == 0) ? tot[0] : (kg == 1) ? tot[1] : (kg == 2) ? tot[2] : tot[3];
        s += s_boP;
        float E = __builtin_amdgcn_exp2f(s);
        out[base + lane] = __builtin_amdgcn_rcpf(1.0f + E);
    }
}

extern "C" void kernel_launch(void* const* d_in, const int* in_sizes, int n_in,
                              void* d_out, int out_size, void* d_ws, size_t ws_size,
                              hipStream_t stream) {
    const float* x  = (const float*)d_in[0];
    const float* W0 = (const float*)d_in[1];
    const float* b0 = (const float*)d_in[2];
    const float* Wh = (const float*)d_in[3];
    const float* bh = (const float*)d_in[4];
    const float* Wo = (const float*)d_in[5];
    const float* bo = (const float*)d_in[6];
    float* out = (float*)d_out;

    int n = out_size;                           // 2097152 = 2048 * 1024, exact
    int block = 256;                            // 4 waves
    long ptsPerBlock = 4L * 64 * CHUNKS;        // 1024
    int grid = (int)((n + ptsPerBlock - 1) / ptsPerBlock);   // 2048 = 8/CU
    cppn_kernel<<<grid, block, 0, stream>>>(x, W0, b0, Wh, bh, Wo, bo, out);
}